// Round 15
// baseline (151.144 us; speedup 1.0000x reference)
//
#include <hip/hip_runtime.h>
#include <math.h>

#define LL 8192
#define DD 1024
#define DH 128

typedef unsigned long long u64;
typedef __attribute__((ext_vector_type(8))) short bf16x8;
typedef __attribute__((ext_vector_type(4))) float f32x4;

__device__ __forceinline__ unsigned f2bf(float f) {
  unsigned u = __float_as_uint(f);
  u = (u + 0x7fffu + ((u >> 16) & 1u)) >> 16;  // RNE to bf16
  return u;
}

// ---------------- fdlibm/glibc s_atanf.c bitwise port -----------------------
__device__ __forceinline__ float fdlibm_atanf(float x) {
#pragma clang fp contract(off)
  const float atanhi0 = __uint_as_float(0x3eed6338u);
  const float atanhi1 = __uint_as_float(0x3f490fdau);
  const float atanhi2 = __uint_as_float(0x3f7b985eu);
  const float atanhi3 = __uint_as_float(0x3fc90fdau);
  const float atanlo0 = __uint_as_float(0x31ac3769u);
  const float atanlo1 = __uint_as_float(0x33222168u);
  const float atanlo2 = __uint_as_float(0x33140fb4u);
  const float atanlo3 = __uint_as_float(0x33a22168u);
  const float aT0 = __uint_as_float(0x3eaaaaa9u);
  const float aT1 = __uint_as_float(0xbe4cca98u);
  const float aT2 = __uint_as_float(0x3e11f50du);
  const float aT3 = __uint_as_float(0xbdda1247u);
  const float aT4 = __uint_as_float(0x3d7cac25u);
  unsigned hx = __float_as_uint(x);
  unsigned ix = hx & 0x7fffffffu;
  int id;
  if (ix >= 0x4c800000u) {
    if (ix > 0x7f800000u) return x + x;
    float z = atanhi3 + atanlo3;
    return (hx >> 31) ? -z : z;
  }
  if (ix < 0x3ee00000u) {
    if (ix < 0x39800000u) return x;
    id = -1;
  } else {
    x = fabsf(x);
    if (ix < 0x3f980000u) {
      if (ix < 0x3f300000u) { id = 0; x = (2.0f * x - 1.0f) / (2.0f + x); }
      else                  { id = 1; x = (x - 1.0f) / (x + 1.0f); }
    } else {
      if (ix < 0x401c0000u) { id = 2; x = (x - 1.5f) / (1.0f + 1.5f * x); }
      else                  { id = 3; x = -1.0f / x; }
    }
  }
  float z = x * x;
  float w = z * z;
  float s1 = z * (aT0 + w * (aT2 + w * aT4));
  float s2 = w * (aT1 + w * aT3);
  if (id < 0) return x - x * (s1 + s2);
  float r;
  if (id == 0)      r = atanhi0 - ((x * (s1 + s2) - atanlo0) - x);
  else if (id == 1) r = atanhi1 - ((x * (s1 + s2) - atanlo1) - x);
  else if (id == 2) r = atanhi2 - ((x * (s1 + s2) - atanlo2) - x);
  else              r = atanhi3 - ((x * (s1 + s2) - atanlo3) - x);
  return (hx >> 31) ? -r : r;
}

// ---------------- Kernel 1: keys (FROZEN math) + W pack + slab-linear xc ----
// xc emission: per h-slab, the block's 32 rows are CONTIGUOUS 8KB in xc
// ([b][h][l][128], l consecutive). Threads re-read x from L2/L3 (block's own
// 128KB slice, just touched) and write 2 x uint4 each, block-linear -> fully
// coalesced. No LDS exchange, no extra barriers, no persistent registers.
template <int XC>
__global__ __launch_bounds__(256) void k_keys(const float* __restrict__ x,
                                              const float* __restrict__ hw,
                                              const float* __restrict__ hb,
                                              u64* __restrict__ ks,
                                              const float* __restrict__ cw,
                                              unsigned short* __restrict__ wb,
                                              unsigned short* __restrict__ xc) {
  __shared__ float2 wL[128][8];
  __shared__ float projL[32][16];
  const int tid = threadIdx.x;
  const float2* hw2 = (const float2*)hw;
  for (int i = tid; i < 1024; i += 256) {
    int hh = i >> 7, dd = i & 127;
    wL[dd][hh] = hw2[i];
  }
  __syncthreads();
  const int r = tid >> 3;
  const int h = tid & 7;
  const int m = blockIdx.x * 32 + r;
  const int b = m >> 13, l = m & (LL - 1);
  const float4* xp = (const float4*)(x + (size_t)m * DD + h * DH);
  float a0 = 0.f, a1 = 0.f;
#pragma unroll
  for (int q = 0; q < 32; ++q) {
    float4 v = xp[q];
    float2 w0 = wL[q * 4 + 0][h];
    float2 w1 = wL[q * 4 + 1][h];
    float2 w2 = wL[q * 4 + 2][h];
    float2 w3 = wL[q * 4 + 3][h];
    a0 = fmaf(v.x, w0.x, a0); a1 = fmaf(v.x, w0.y, a1);
    a0 = fmaf(v.y, w1.x, a0); a1 = fmaf(v.y, w1.y, a1);
    a0 = fmaf(v.z, w2.x, a0); a1 = fmaf(v.z, w2.y, a1);
    a0 = fmaf(v.w, w3.x, a0); a1 = fmaf(v.w, w3.y, a1);
  }
  projL[r][h * 2 + 0] = a0;
  projL[r][h * 2 + 1] = a1;
  __syncthreads();
  const int j = h;
  float px = projL[r][j] + hb[j];
  float py = projL[r][8 + j] + hb[8 + j];
  float den = py + 1e-4f;
  float ratio = px / den;
  float angle = fdlibm_atanf(ratio);
  unsigned am = __float_as_uint(angle);
  am = (am & 0x80000000u) ? ~am : (am | 0x80000000u);
  ks[((size_t)b * 8 + j) * LL + l] = ((u64)am << 13) | (u64)l;
  // ---- slab-linear xc emission (re-read x from cache) ----
  if (XC) {
    const int m0 = blockIdx.x * 32;
    const int b0 = m0 >> 13, l0 = m0 & (LL - 1);
#pragma unroll 1
    for (int c = 0; c < 8; ++c) {
      unsigned short* slab = xc + ((size_t)(b0 * 8 + c) * LL + l0) * DH;
#pragma unroll
      for (int u = tid; u < 512; u += 256) {  // uint4 index within 8KB slab
        int lr = u >> 4;           // local row 0..31
        int d0 = (u & 15) * 8;     // element 0,8,..,120
        const float4* sp = (const float4*)(x + ((size_t)(m0 + lr)) * DD + c * DH + d0);
        float4 v0 = sp[0], v1 = sp[1];
        uint4 o;
        o.x = f2bf(v0.x) | (f2bf(v0.y) << 16);
        o.y = f2bf(v0.z) | (f2bf(v0.w) << 16);
        o.z = f2bf(v1.x) | (f2bf(v1.y) << 16);
        o.w = f2bf(v1.z) | (f2bf(v1.w) << 16);
        *(uint4*)(slab + u * 8) = o;
      }
    }
  }
  // ---- fused W pack (independent; 384 items per block) ----
  {
    int base = blockIdx.x * 384;
    for (int g = base + tid; g < base + 384; g += 256) {
      int hh = g / 49152;
      int rem = g % 49152;
      int kk = rem >> 12;
      int rem2 = rem & 4095;
      int n = rem2 >> 9;
      int rem3 = rem2 & 511;
      int l2 = rem3 >> 3;
      int j2 = rem3 & 7;
      int k = kk * 32 + ((l2 >> 4) * 8) + j2;
      int o = n * 16 + (l2 & 15);
      int t = k >> 7, i2 = k & 127;
      wb[g] = (unsigned short)f2bf(cw[((size_t)(hh * 128 + o)) * 384 + i2 * 3 + t]);
    }
  }
}

// ---------------- Sort: same bitonic network, stride-decomposed (FROZEN) ----
__global__ __launch_bounds__(256) void k_sort_loc512(u64* __restrict__ ks) {
  __shared__ u64 sk[512];  // 4 KB
  const int blk = blockIdx.x;             // 512 = 32 segs * 16 chunks
  const int seg = blk >> 4, c = blk & 15;
  u64* base = ks + (size_t)seg * LL + c * 512;
  const int tid = threadIdx.x;
  sk[tid] = base[tid];
  sk[tid + 256] = base[tid + 256];
  __syncthreads();
  const int cb = c * 512;
  for (int size = 2; size <= 512; size <<= 1) {
    for (int stride = size >> 1; stride > 0; stride >>= 1) {
      int i = 2 * tid - (tid & (stride - 1));
      int j = i + stride;
      bool up = (((cb + i) & size) == 0);
      u64 a = sk[i], d = sk[j];
      if ((a > d) == up) { sk[i] = d; sk[j] = a; }
      __syncthreads();
    }
  }
  base[tid] = sk[tid];
  base[tid + 256] = sk[tid + 256];
}

__global__ __launch_bounds__(1024) void k_sort_loc2k(u64* __restrict__ ks) {
  __shared__ u64 sk[2048];  // 16 KB
  const int blk = blockIdx.x;             // 128 = 32 segs * 4 chunks
  const int seg = blk >> 2, c = blk & 3;
  u64* base = ks + (size_t)seg * LL + c * 2048;
  const int tid = threadIdx.x;
  sk[tid] = base[tid];
  sk[tid + 1024] = base[tid + 1024];
  __syncthreads();
  const int cb = c * 2048;
  for (int size = 1024; size <= 2048; size <<= 1) {
    for (int stride = size >> 1; stride > 0; stride >>= 1) {
      int i = 2 * tid - (tid & (stride - 1));
      int j = i + stride;
      bool up = (((cb + i) & size) == 0);
      u64 a = sk[i], d = sk[j];
      if ((a > d) == up) { sk[i] = d; sk[j] = a; }
      __syncthreads();
    }
  }
  base[tid] = sk[tid];
  base[tid + 1024] = sk[tid + 1024];
}

__global__ __launch_bounds__(1024) void k_sort_t4k(u64* __restrict__ ks) {
  __shared__ u64 sk[4096];  // 32 KB
  const int blk = blockIdx.x;             // 64 = 32 segs * 2 chunks
  const int seg = blk >> 1, c = blk & 1;
  u64* base = ks + (size_t)seg * LL + c * 4096;
  const int tid = threadIdx.x;
#pragma unroll
  for (int i = 0; i < 4; ++i) sk[tid + i * 1024] = base[tid + i * 1024];
  __syncthreads();
  const int cb = c * 4096;
  for (int stride = 2048; stride > 0; stride >>= 1) {
#pragma unroll
    for (int pp = 0; pp < 2; ++pp) {
      int p = tid + pp * 1024;
      int i = 2 * p - (p & (stride - 1));
      int j = i + stride;
      bool up = (((cb + i) & 4096) == 0);
      u64 a = sk[i], d = sk[j];
      if ((a > d) == up) { sk[i] = d; sk[j] = a; }
    }
    __syncthreads();
  }
#pragma unroll
  for (int i = 0; i < 4; ++i) base[tid + i * 1024] = sk[tid + i * 1024];
}

__global__ __launch_bounds__(256) void k_sort_g8(u64* __restrict__ ks) {
  int t = blockIdx.x * 256 + threadIdx.x;  // 65536 = 32 segs * 2048
  int seg = t >> 11, i = t & 2047;
  u64* base = ks + (size_t)seg * LL;
  u64 e0 = base[i], e1 = base[i + 2048], e2 = base[i + 4096], e3 = base[i + 6144];
  u64 tt;
  if (e0 > e2) { tt = e0; e0 = e2; e2 = tt; }  // stride 4096
  if (e1 > e3) { tt = e1; e1 = e3; e3 = tt; }
  if (e0 > e1) { tt = e0; e0 = e1; e1 = tt; }  // stride 2048
  if (e2 > e3) { tt = e2; e2 = e3; e3 = tt; }
  base[i] = e0; base[i + 2048] = e1; base[i + 4096] = e2; base[i + 6144] = e3;
}

__global__ __launch_bounds__(1024) void k_sort_tail(u64* __restrict__ ks,
                                                    int size,
                                                    int* __restrict__ perm) {
  __shared__ u64 sk[2048];
  const int blk = blockIdx.x;
  const int seg = blk >> 2, c = blk & 3;
  u64* base = ks + (size_t)seg * LL + c * 2048;
  const int tid = threadIdx.x;
  sk[tid] = base[tid];
  sk[tid + 1024] = base[tid + 1024];
  __syncthreads();
  const int cb = c * 2048;
  for (int stride = 1024; stride > 0; stride >>= 1) {
    int i = 2 * tid - (tid & (stride - 1));
    int j = i + stride;
    bool up = (((cb + i) & size) == 0);
    u64 a = sk[i], d = sk[j];
    if ((a > d) == up) { sk[i] = d; sk[j] = a; }
    __syncthreads();
  }
  if (perm) {
    int* dst = perm + (size_t)seg * LL + c * 2048;
    dst[tid] = (int)(sk[tid] & (u64)(LL - 1));
    dst[tid + 1024] = (int)(sk[tid + 1024] & (u64)(LL - 1));
  } else {
    base[tid] = sk[tid];
    base[tid + 1024] = sk[tid + 1024];
  }
}

// ---------------- Kernel 4: MFMA conv — R6 shape + Ps prefetch + xc gather --
// (FROZEN — ran ~37us with xc)
template <int XC>
__global__ __launch_bounds__(256) void k_conv(const float* __restrict__ x,
                                              const unsigned short* __restrict__ xc,
                                              const unsigned short* __restrict__ wb,
                                              const float* __restrict__ bias,
                                              const int* __restrict__ perm,
                                              float* __restrict__ out) {
  __shared__ short Xs[66 * 136];   // 17952 B
  __shared__ short Ws[8 * 64 * 8]; // 8192 B
  __shared__ int Ps2[66];
  const int tid = threadIdx.x;
  const int bid = blockIdx.x;      // 4*8*128
  const int tile = bid & 127;
  const int h = (bid >> 7) & 7;
  const int b = bid >> 10;
  const int r0 = tile * 64;
  const int* pbh = perm + ((size_t)b * 8 + h) * LL;
  if (tid < 66) Ps2[tid] = pbh[(r0 + tid - 1 + LL) & (LL - 1)];
  __syncthreads();
  {
    const int ln = tid & 31;
    if (XC) {
      const unsigned short* xcb = xc + ((size_t)(b * 8 + h)) * LL * DH;
      for (int j = (tid >> 5); j < 66; j += 8) {
        const uint2* sp = (const uint2*)(xcb + (size_t)Ps2[j] * DH);
        *(uint2*)(Xs + j * 136 + ln * 4) = sp[ln];
      }
    } else {
      for (int j = (tid >> 5); j < 66; j += 8) {
        int src = Ps2[j];
        float4 v = ((const float4*)(x + ((size_t)(b * LL + src)) * DD + h * DH))[ln];
        uint2 pk;
        pk.x = f2bf(v.x) | (f2bf(v.y) << 16);
        pk.y = f2bf(v.z) | (f2bf(v.w) << 16);
        *(uint2*)(Xs + j * 136 + ln * 4) = pk;
      }
    }
  }
  const int w = tid >> 6;
  const int l = tid & 63;
  const int arow = w * 16 + (l & 15);
  const int acol = (l >> 4) * 8;
  f32x4 acc[8];
#pragma unroll
  for (int n = 0; n < 8; ++n) acc[n] = (f32x4){0.f, 0.f, 0.f, 0.f};
  const uint4* wsrc = (const uint4*)(wb + (size_t)h * 49152);
  uint4* Ws16 = (uint4*)Ws;
  for (int kk = 0; kk < 12; ++kk) {
    __syncthreads();
    Ws16[tid] = wsrc[kk * 512 + tid];
    Ws16[tid + 256] = wsrc[kk * 512 + tid + 256];
    __syncthreads();
    bf16x8 af = *(const bf16x8*)(Xs + (arow + (kk >> 2)) * 136 + (kk & 3) * 32 + acol);
#pragma unroll
    for (int n = 0; n < 8; ++n) {
      bf16x8 bf_ = *(const bf16x8*)(Ws + (n * 64 + l) * 8);
      acc[n] = __builtin_amdgcn_mfma_f32_16x16x32_bf16(af, bf_, acc[n], 0, 0, 0);
    }
  }
  // epilogue: C layout col=lane&15, row=(lane>>4)*4+reg (m89-verified)
  int dsts[4];
#pragma unroll
  for (int reg = 0; reg < 4; ++reg) dsts[reg] = Ps2[1 + w * 16 + (l >> 4) * 4 + reg];
#pragma unroll
  for (int n = 0; n < 8; ++n) {
    int o = h * DH + n * 16 + (l & 15);
    float bv = bias[o];
#pragma unroll
    for (int reg = 0; reg < 4; ++reg) {
      out[((size_t)(b * LL + dsts[reg])) * DD + o] = acc[n][reg] + bv;
    }
  }
}

extern "C" void kernel_launch(void* const* d_in, const int* in_sizes, int n_in,
                              void* d_out, int out_size, void* d_ws, size_t ws_size,
                              hipStream_t stream) {
  const float* x  = (const float*)d_in[0];
  const float* hw = (const float*)d_in[1];
  const float* hb = (const float*)d_in[2];
  const float* cw = (const float*)d_in[3];
  const float* cb = (const float*)d_in[4];
  float* out = (float*)d_out;
  // workspace: ks 2MB | perm 1MB | Wb 0.77MB | xc(bf16 copy) 67MB @ +4MB
  u64* ks   = (u64*)d_ws;
  int* perm = (int*)((char*)d_ws + (2u << 20));
  unsigned short* wbp = (unsigned short*)((char*)d_ws + (3u << 20));
  const size_t XC_OFF = (size_t)4 << 20;
  const size_t XC_BYTES = (size_t)4 * 8 * LL * DH * 2;  // 67.1 MB
  bool use_xc = ws_size >= XC_OFF + XC_BYTES;
  unsigned short* xcp = (unsigned short*)((char*)d_ws + XC_OFF);

  if (use_xc) k_keys<1><<<1024, 256, 0, stream>>>(x, hw, hb, ks, cw, wbp, xcp);
  else        k_keys<0><<<1024, 256, 0, stream>>>(x, hw, hb, ks, cw, wbp, nullptr);
  // bitonic network, stride-decomposed (identical compare sequence):
  k_sort_loc512<<<512, 256, 0, stream>>>(ks);            // sizes 2..512
  k_sort_loc2k<<<128, 1024, 0, stream>>>(ks);            // sizes 1024..2048
  k_sort_t4k<<<64, 1024, 0, stream>>>(ks);               // size 4096 complete
  k_sort_g8<<<256, 256, 0, stream>>>(ks);                // size 8192, strides 4096+2048
  k_sort_tail<<<128, 1024, 0, stream>>>(ks, 8192, perm); // size 8192, strides 1024..1 + perm
  if (use_xc) k_conv<1><<<4096, 256, 0, stream>>>(x, xcp, wbp, cb, perm, out);
  else        k_conv<0><<<4096, 256, 0, stream>>>(x, nullptr, wbp, cb, perm, out);
}

// Round 16
// 118.334 us; speedup vs baseline: 1.2773x; 1.2773x over previous
//
#include <hip/hip_runtime.h>
#include <math.h>

#define LL 8192
#define DD 1024
#define DH 128

typedef unsigned long long u64;
typedef __attribute__((ext_vector_type(8))) short bf16x8;
typedef __attribute__((ext_vector_type(4))) float f32x4;

__device__ __forceinline__ unsigned f2bf(float f) {
  unsigned u = __float_as_uint(f);
  u = (u + 0x7fffu + ((u >> 16) & 1u)) >> 16;  // RNE to bf16
  return u;
}

// ---------------- fdlibm/glibc s_atanf.c bitwise port -----------------------
__device__ __forceinline__ float fdlibm_atanf(float x) {
#pragma clang fp contract(off)
  const float atanhi0 = __uint_as_float(0x3eed6338u);
  const float atanhi1 = __uint_as_float(0x3f490fdau);
  const float atanhi2 = __uint_as_float(0x3f7b985eu);
  const float atanhi3 = __uint_as_float(0x3fc90fdau);
  const float atanlo0 = __uint_as_float(0x31ac3769u);
  const float atanlo1 = __uint_as_float(0x33222168u);
  const float atanlo2 = __uint_as_float(0x33140fb4u);
  const float atanlo3 = __uint_as_float(0x33a22168u);
  const float aT0 = __uint_as_float(0x3eaaaaa9u);
  const float aT1 = __uint_as_float(0xbe4cca98u);
  const float aT2 = __uint_as_float(0x3e11f50du);
  const float aT3 = __uint_as_float(0xbdda1247u);
  const float aT4 = __uint_as_float(0x3d7cac25u);
  unsigned hx = __float_as_uint(x);
  unsigned ix = hx & 0x7fffffffu;
  int id;
  if (ix >= 0x4c800000u) {
    if (ix > 0x7f800000u) return x + x;
    float z = atanhi3 + atanlo3;
    return (hx >> 31) ? -z : z;
  }
  if (ix < 0x3ee00000u) {
    if (ix < 0x39800000u) return x;
    id = -1;
  } else {
    x = fabsf(x);
    if (ix < 0x3f980000u) {
      if (ix < 0x3f300000u) { id = 0; x = (2.0f * x - 1.0f) / (2.0f + x); }
      else                  { id = 1; x = (x - 1.0f) / (x + 1.0f); }
    } else {
      if (ix < 0x401c0000u) { id = 2; x = (x - 1.5f) / (1.0f + 1.5f * x); }
      else                  { id = 3; x = -1.0f / x; }
    }
  }
  float z = x * x;
  float w = z * z;
  float s1 = z * (aT0 + w * (aT2 + w * aT4));
  float s2 = w * (aT1 + w * aT3);
  if (id < 0) return x - x * (s1 + s2);
  float r;
  if (id == 0)      r = atanhi0 - ((x * (s1 + s2) - atanlo0) - x);
  else if (id == 1) r = atanhi1 - ((x * (s1 + s2) - atanlo1) - x);
  else if (id == 2) r = atanhi2 - ((x * (s1 + s2) - atanlo2) - x);
  else              r = atanhi3 - ((x * (s1 + s2) - atanlo3) - x);
  return (hx >> 31) ? -r : r;
}

// ---------------- Kernel 1: keys (FROZEN math) + fused W pack (R9 exact) ----
__global__ __launch_bounds__(256) void k_keys(const float* __restrict__ x,
                                              const float* __restrict__ hw,
                                              const float* __restrict__ hb,
                                              u64* __restrict__ ks,
                                              const float* __restrict__ cw,
                                              unsigned short* __restrict__ wb) {
  __shared__ float2 wL[128][8];
  __shared__ float projL[32][16];
  const int tid = threadIdx.x;
  const float2* hw2 = (const float2*)hw;
  for (int i = tid; i < 1024; i += 256) {
    int hh = i >> 7, dd = i & 127;
    wL[dd][hh] = hw2[i];
  }
  __syncthreads();
  const int r = tid >> 3;
  const int h = tid & 7;
  const int m = blockIdx.x * 32 + r;
  const int b = m >> 13, l = m & (LL - 1);
  const float4* xp = (const float4*)(x + (size_t)m * DD + h * DH);
  float a0 = 0.f, a1 = 0.f;
#pragma unroll
  for (int q = 0; q < 32; ++q) {
    float4 v = xp[q];
    float2 w0 = wL[q * 4 + 0][h];
    float2 w1 = wL[q * 4 + 1][h];
    float2 w2 = wL[q * 4 + 2][h];
    float2 w3 = wL[q * 4 + 3][h];
    a0 = fmaf(v.x, w0.x, a0); a1 = fmaf(v.x, w0.y, a1);
    a0 = fmaf(v.y, w1.x, a0); a1 = fmaf(v.y, w1.y, a1);
    a0 = fmaf(v.z, w2.x, a0); a1 = fmaf(v.z, w2.y, a1);
    a0 = fmaf(v.w, w3.x, a0); a1 = fmaf(v.w, w3.y, a1);
  }
  projL[r][h * 2 + 0] = a0;
  projL[r][h * 2 + 1] = a1;
  __syncthreads();
  const int j = h;
  float px = projL[r][j] + hb[j];
  float py = projL[r][8 + j] + hb[8 + j];
  float den = py + 1e-4f;
  float ratio = px / den;
  float angle = fdlibm_atanf(ratio);
  unsigned am = __float_as_uint(angle);
  am = (am & 0x80000000u) ? ~am : (am | 0x80000000u);
  ks[((size_t)b * 8 + j) * LL + l] = ((u64)am << 13) | (u64)l;
  // ---- fused W pack (independent; 384 items per block) ----
  {
    int base = blockIdx.x * 384;
    for (int g = base + tid; g < base + 384; g += 256) {
      int hh = g / 49152;
      int rem = g % 49152;
      int kk = rem >> 12;
      int rem2 = rem & 4095;
      int n = rem2 >> 9;
      int rem3 = rem2 & 511;
      int l2 = rem3 >> 3;
      int j2 = rem3 & 7;
      int k = kk * 32 + ((l2 >> 4) * 8) + j2;
      int o = n * 16 + (l2 & 15);
      int t = k >> 7, i2 = k & 127;
      wb[g] = (unsigned short)f2bf(cw[((size_t)(hh * 128 + o)) * 384 + i2 * 3 + t]);
    }
  }
}

// ---------------- Sort: same bitonic network, stride-decomposed -------------
__global__ __launch_bounds__(256) void k_sort_loc512(u64* __restrict__ ks) {
  __shared__ u64 sk[512];  // 4 KB
  const int blk = blockIdx.x;             // 512 = 32 segs * 16 chunks
  const int seg = blk >> 4, c = blk & 15;
  u64* base = ks + (size_t)seg * LL + c * 512;
  const int tid = threadIdx.x;
  sk[tid] = base[tid];
  sk[tid + 256] = base[tid + 256];
  __syncthreads();
  const int cb = c * 512;
  for (int size = 2; size <= 512; size <<= 1) {
    for (int stride = size >> 1; stride > 0; stride >>= 1) {
      int i = 2 * tid - (tid & (stride - 1));
      int j = i + stride;
      bool up = (((cb + i) & size) == 0);
      u64 a = sk[i], d = sk[j];
      if ((a > d) == up) { sk[i] = d; sk[j] = a; }
      __syncthreads();
    }
  }
  base[tid] = sk[tid];
  base[tid + 256] = sk[tid + 256];
}

__global__ __launch_bounds__(1024) void k_sort_loc2k(u64* __restrict__ ks) {
  __shared__ u64 sk[2048];  // 16 KB
  const int blk = blockIdx.x;             // 128 = 32 segs * 4 chunks
  const int seg = blk >> 2, c = blk & 3;
  u64* base = ks + (size_t)seg * LL + c * 2048;
  const int tid = threadIdx.x;
  sk[tid] = base[tid];
  sk[tid + 1024] = base[tid + 1024];
  __syncthreads();
  const int cb = c * 2048;
  for (int size = 1024; size <= 2048; size <<= 1) {
    for (int stride = size >> 1; stride > 0; stride >>= 1) {
      int i = 2 * tid - (tid & (stride - 1));
      int j = i + stride;
      bool up = (((cb + i) & size) == 0);
      u64 a = sk[i], d = sk[j];
      if ((a > d) == up) { sk[i] = d; sk[j] = a; }
      __syncthreads();
    }
  }
  base[tid] = sk[tid];
  base[tid + 1024] = sk[tid + 1024];
}

__global__ __launch_bounds__(1024) void k_sort_t4k(u64* __restrict__ ks) {
  __shared__ u64 sk[4096];  // 32 KB
  const int blk = blockIdx.x;             // 64 = 32 segs * 2 chunks
  const int seg = blk >> 1, c = blk & 1;
  u64* base = ks + (size_t)seg * LL + c * 4096;
  const int tid = threadIdx.x;
#pragma unroll
  for (int i = 0; i < 4; ++i) sk[tid + i * 1024] = base[tid + i * 1024];
  __syncthreads();
  const int cb = c * 4096;
  for (int stride = 2048; stride > 0; stride >>= 1) {
#pragma unroll
    for (int pp = 0; pp < 2; ++pp) {
      int p = tid + pp * 1024;
      int i = 2 * p - (p & (stride - 1));
      int j = i + stride;
      bool up = (((cb + i) & 4096) == 0);
      u64 a = sk[i], d = sk[j];
      if ((a > d) == up) { sk[i] = d; sk[j] = a; }
    }
    __syncthreads();
  }
#pragma unroll
  for (int i = 0; i < 4; ++i) base[tid + i * 1024] = sk[tid + i * 1024];
}

// tailg8: size-8192 stage complete. Fuses g8 (strides 4096+2048 via 4-elem
// closure — exact same compare network, recomputed per block; RACE-FREE since
// output goes only to perm, ks is never written) + strides 1024..1 in LDS.
__global__ __launch_bounds__(1024) void k_sort_tailg8(const u64* __restrict__ ks,
                                                      int* __restrict__ perm) {
  __shared__ u64 sk[2048];
  const int blk = blockIdx.x;             // 128 = 32 segs * 4 chunks
  const int seg = blk >> 2, c = blk & 3;
  const u64* base = ks + (size_t)seg * LL;
  const int tid = threadIdx.x;
#pragma unroll
  for (int s = 0; s < 2; ++s) {
    int i = tid + s * 1024;  // slot within chunk
    u64 e0 = base[i], e1 = base[i + 2048], e2 = base[i + 4096], e3 = base[i + 6144];
    u64 tt;
    if (e0 > e2) { tt = e0; e0 = e2; e2 = tt; }  // stride 4096
    if (e1 > e3) { tt = e1; e1 = e3; e3 = tt; }
    if (e0 > e1) { tt = e0; e0 = e1; e1 = tt; }  // stride 2048
    if (e2 > e3) { tt = e2; e2 = e3; e3 = tt; }
    sk[i] = (c == 0) ? e0 : (c == 1) ? e1 : (c == 2) ? e2 : e3;
  }
  __syncthreads();
  // strides 1024..1; size 8192 => up always true within segment
  for (int stride = 1024; stride > 0; stride >>= 1) {
    int i = 2 * tid - (tid & (stride - 1));
    int j = i + stride;
    u64 a = sk[i], d = sk[j];
    if (a > d) { sk[i] = d; sk[j] = a; }
    __syncthreads();
  }
  int* dst = perm + (size_t)seg * LL + c * 2048;
  dst[tid] = (int)(sk[tid] & (u64)(LL - 1));
  dst[tid + 1024] = (int)(sk[tid + 1024] & (u64)(LL - 1));
}

// ---------------- Kernel 4: MFMA conv — R6 shape + T14 W-prefetch -----------
// EXACT R6/R9 tiling, MFMA sequence, and LDS layout (proven local optimum).
// Single change: next W chunk's 2 x uint4 are loaded into REGISTERS before
// the MFMA cluster (T14 async-stage split) — global latency hides under
// MFMAs instead of sitting between the barriers. Bit-identical results.
__global__ __launch_bounds__(256) void k_conv(const float* __restrict__ x,
                                              const unsigned short* __restrict__ wb,
                                              const float* __restrict__ bias,
                                              const int* __restrict__ perm,
                                              float* __restrict__ out) {
  __shared__ short Xs[66 * 136];   // 17952 B
  __shared__ short Ws[8 * 64 * 8]; // 8192 B
  __shared__ int Ps2[66];
  const int tid = threadIdx.x;
  const int bid = blockIdx.x;      // 4*8*128
  const int tile = bid & 127;
  const int h = (bid >> 7) & 7;
  const int b = bid >> 10;
  const int r0 = tile * 64;
  const int* pbh = perm + ((size_t)b * 8 + h) * LL;
  if (tid < 66) Ps2[tid] = pbh[(r0 + tid - 1 + LL) & (LL - 1)];
  const uint4* wsrc = (const uint4*)(wb + (size_t)h * 49152);
  uint4 wr0 = wsrc[tid];           // prologue: chunk 0 staged in regs
  uint4 wr1 = wsrc[tid + 256];
  __syncthreads();                 // Ps2 visible
  {
    const int ln = tid & 31;
    for (int j = (tid >> 5); j < 66; j += 8) {
      int src = Ps2[j];
      float4 v = ((const float4*)(x + ((size_t)(b * LL + src)) * DD + h * DH))[ln];
      uint2 pk;
      pk.x = f2bf(v.x) | (f2bf(v.y) << 16);
      pk.y = f2bf(v.z) | (f2bf(v.w) << 16);
      *(uint2*)(Xs + j * 136 + ln * 4) = pk;
    }
  }
  const int w = tid >> 6;
  const int l = tid & 63;
  const int arow = w * 16 + (l & 15);
  const int acol = (l >> 4) * 8;
  f32x4 acc[8];
#pragma unroll
  for (int n = 0; n < 8; ++n) acc[n] = (f32x4){0.f, 0.f, 0.f, 0.f};
  uint4* Ws16 = (uint4*)Ws;
  for (int kk = 0; kk < 12; ++kk) {
    __syncthreads();               // kk=0: Xs ready; kk>0: prev MFMAs done with Ws
    Ws16[tid] = wr0;
    Ws16[tid + 256] = wr1;
    __syncthreads();               // Ws ready
    if (kk < 11) {                 // T14: issue next chunk loads BEFORE MFMAs
      wr0 = wsrc[(kk + 1) * 512 + tid];
      wr1 = wsrc[(kk + 1) * 512 + tid + 256];
    }
    bf16x8 af = *(const bf16x8*)(Xs + (arow + (kk >> 2)) * 136 + (kk & 3) * 32 + acol);
#pragma unroll
    for (int n = 0; n < 8; ++n) {
      bf16x8 bf_ = *(const bf16x8*)(Ws + (n * 64 + l) * 8);
      acc[n] = __builtin_amdgcn_mfma_f32_16x16x32_bf16(af, bf_, acc[n], 0, 0, 0);
    }
  }
  // epilogue: C layout col=lane&15, row=(lane>>4)*4+reg (m89-verified)
  int dsts[4];
#pragma unroll
  for (int reg = 0; reg < 4; ++reg) dsts[reg] = Ps2[1 + w * 16 + (l >> 4) * 4 + reg];
#pragma unroll
  for (int n = 0; n < 8; ++n) {
    int o = h * DH + n * 16 + (l & 15);
    float bv = bias[o];
#pragma unroll
    for (int reg = 0; reg < 4; ++reg) {
      out[((size_t)(b * LL + dsts[reg])) * DD + o] = acc[n][reg] + bv;
    }
  }
}

extern "C" void kernel_launch(void* const* d_in, const int* in_sizes, int n_in,
                              void* d_out, int out_size, void* d_ws, size_t ws_size,
                              hipStream_t stream) {
  const float* x  = (const float*)d_in[0];
  const float* hw = (const float*)d_in[1];
  const float* hb = (const float*)d_in[2];
  const float* cw = (const float*)d_in[3];
  const float* cb = (const float*)d_in[4];
  float* out = (float*)d_out;
  // workspace: ks 2MB | perm 1MB | Wb(bf16 fragment-packed) 0.77MB
  u64* ks   = (u64*)d_ws;
  int* perm = (int*)((char*)d_ws + (2u << 20));
  unsigned short* wbp = (unsigned short*)((char*)d_ws + (3u << 20));

  k_keys<<<1024, 256, 0, stream>>>(x, hw, hb, ks, cw, wbp);  // keys + W pack
  // bitonic network, stride-decomposed (identical compare sequence):
  k_sort_loc512<<<512, 256, 0, stream>>>(ks);             // sizes 2..512
  k_sort_loc2k<<<128, 1024, 0, stream>>>(ks);             // sizes 1024..2048
  k_sort_t4k<<<64, 1024, 0, stream>>>(ks);                // size 4096 complete
  k_sort_tailg8<<<128, 1024, 0, stream>>>(ks, perm);      // size 8192 complete + perm
  k_conv<<<4096, 256, 0, stream>>>(x, wbp, cb, perm, out);
}